// Round 12
// baseline (136.612 us; speedup 1.0000x reference)
//
#include <hip/hip_runtime.h>

// Problem constants (from reference)
#define HH 256
#define WW 336
#define HWPIX (HH * WW)          // 86016
#define BATCH 8
#define NEV 262144               // 2^18
#define NEV_SHIFT 18
#define FLOW_SCALING 336.0f
#define REG_WEIGHT 0.001f

// 8-row bands: items binned directly at accum granularity.
#define BANDS 32
#define BANDSHIFT 3
#define BANDROWS 8
#define NBINS (2 * BATCH * BANDS)  // 512 bins: ((tr*8+b)*32+band)
#define CAP 14336                  // slots/bin; mean ~9.2K (multiple of 4)
#define GSTRIDE 16                 // u32 stride/bin: 64B line per counter

// bin_events geometry: 1024 threads x 2 events/thread = 2048 events/block.
// sval worst case = 2048 ev * 2 tref * 2 bands = 8192, + <=192 pad items
// (4-alignment) -> 8384 (65.5 KB LDS); 2 blocks/CU, 32 waves/CU.
// Barrier structure: [zero]bar[count]bar[all-wave reg scan + stage]bar[flush]
// -- the scan is replicated per-wave in registers (6 shfl_up) so the
// stage phase needs no extra barrier and no 15-idle-wave scan phase.
#define BE_THREADS 1024
#define EVPT 2
#define EV_PER_BLOCK (BE_THREADS * EVPT)
#define MAXITEMS 8384

// bin_accum geometry: one block per bin, full 8-row tile in LDS
#define HTILE (BANDROWS * WW)      // 2688 u32 per pol
#define NBLK_ACC NBINS             // 512 accum blocks = 2/CU, no tail

// Workspace layout (split 6-byte items: pk u32 + qy u16):
//   [0]       uint   gcount[NBINS*GSTRIDE]   (32 KB, one bin per 64B line)
//   [32768]   float  loss_acc                (4 B)
//   [32772]   uint   done_count              (4 B)
//   [36864]   uint   pk[NBINS*CAP]           (29.4 MB)
//   [after]   u16    qy[NBINS*CAP]           (14.7 MB)
//   [after]   float2 flowi[BATCH * HWPIX]    (5.5 MB) interleaved (fx, fy)
#define GCOUNT_BYTES (NBINS * GSTRIDE * 4)
#define PK_BYTES ((size_t)NBINS * CAP * 4)
#define QY_BYTES ((size_t)NBINS * CAP * 2)

__device__ __forceinline__ float wave_reduce_sum(float v) {
    #pragma unroll
    for (int o = 32; o > 0; o >>= 1) v += __shfl_down(v, o, 64);
    return v;
}

__device__ __forceinline__ float charb(float d) { return sqrtf(d * d + 1e-6f); }

// Pre-pass: pure flow interleave into float2 (single-gather for bin_events)
// + zero gcount/loss_acc/done_count. Smoothness lives in bin_accum where it
// overlaps LDS-atomic straggler latency.
__global__ __launch_bounds__(256)
void flow_prep(const float* __restrict__ flow, float2* __restrict__ flowi,
               unsigned int* __restrict__ gcount, float* __restrict__ loss_acc,
               unsigned int* __restrict__ done_count) {
    int tid = threadIdx.x;
    if (blockIdx.x == 0) {
        for (int i = tid; i < NBINS * GSTRIDE; i += 256) gcount[i] = 0u;
        if (tid == 0) { *loss_acc = 0.0f; *done_count = 0u; }
    }

    const int N4 = BATCH * HWPIX / 4;
    const int H4 = HWPIX / 4;
    for (int i = blockIdx.x * 256 + tid; i < N4; i += gridDim.x * 256) {
        int b = i / H4, u = i - b * H4;
        const float4* ch0 = (const float4*)(flow + (size_t)b * 2 * HWPIX);
        const float4* ch1 = ch0 + H4;
        float4 a0 = ch0[u];    // x-flow (ch 0)
        float4 a1 = ch1[u];    // y-flow (ch 1)

        float4* fo = (float4*)(flowi + (size_t)b * HWPIX);
        fo[2 * u]     = make_float4(a0.x, a1.x, a0.y, a1.y);
        fo[2 * u + 1] = make_float4(a0.z, a1.z, a0.w, a1.w);
    }
}

// Pass 1: warp events, bin by (tr, b, 8-row band); straddling items get one
// copy per band. Per-bin allocations rounded up to x4 (inert pad items:
// pk=0, rowq=15), so every flush quad (i..i+3) is SAME-BIN and 4-aligned.
__global__ __launch_bounds__(BE_THREADS)
void bin_events(const float2* __restrict__ flowi,
                const float4* __restrict__ ev,
                unsigned int* __restrict__ gcount,
                unsigned int* __restrict__ pk_arr,
                unsigned short* __restrict__ qy_arr) {
    __shared__ int lcnt[64];
    __shared__ int loff[64];
    __shared__ int gbase[64];
    __shared__ int stotal;
    __shared__ __align__(16) unsigned long long sval[MAXITEMS];   // 65.5 KB

    int tid = threadIdx.x;
    if (tid < 64) lcnt[tid] = 0;
    __syncthreads();

    int base = blockIdx.x * EV_PER_BLOCK;
    int b = base >> NEV_SHIFT;       // uniform across block (2048 | NEV)
    const float2* fB = flowi + (size_t)b * HWPIX;

    unsigned int pkv[EVPT][2];
    unsigned int hiA[EVPT][2], hiB[EVPT][2];   // qy16 | lb<<16
    int rkA[EVPT][2], rkB[EVPT][2];            // rank or -1

    #pragma unroll
    for (int e = 0; e < EVPT; ++e) {
        int bn = base + e * BE_THREADS + tid;
        float4 ee = ev[bn];          // t, y, x, pol(+/-1)
        float t = ee.x, y = ee.y, x = ee.z;
        unsigned int p = (ee.w > 0.0f) ? 0u : 1u;

        int iy = (int)y, ix = (int)x;
        float2 f = fB[iy * WW + ix];
        float fx = f.x, fy = f.y;

        #pragma unroll
        for (int tr = 0; tr < 2; ++tr) {
            rkA[e][tr] = -1; rkB[e][tr] = -1;
            float tref  = tr ? 0.0f : 1.0f;
            float tg    = tr ? (1.0f - t) : t;
            float dtS = (tref - t) * FLOW_SCALING;
            float wy = fmaf(dtS, fy, y);
            float wx = fmaf(dtS, fx, x);
            if (!(wx > -1.0f && wx < (float)WW)) continue;
            if (!(wy > -1.0f && wy < (float)HH)) continue;

            int ty = (int)floorf(wy);
            int band0 = -1, band1 = -1;
            if (ty >= 0 && ty < HH) band0 = ty >> BANDSHIFT;
            int r1 = ty + 1;
            if (r1 >= 0 && r1 < HH) {
                int bb = r1 >> BANDSHIFT;
                if (bb != band0) band1 = bb;
            }

            unsigned int qx = (unsigned int)(fmaf(wx, 2048.0f, 2048.5f));
            unsigned int qt = (unsigned int)(tg * 2047.0f + 0.5f);
            pkv[e][tr] = (qx << 12) | (qt << 1) | p;

            if (band0 >= 0) {
                float wyrel = wy - (float)(band0 * BANDROWS - 1);   // [1, 9)
                unsigned int qy = (unsigned int)fmaf(wyrel, 2048.0f, 0.5f);
                int lb = tr * BANDS + band0;
                hiA[e][tr] = qy | ((unsigned int)lb << 16);
                rkA[e][tr] = atomicAdd(&lcnt[lb], 1);
            }
            if (band1 >= 0) {
                float wyrel = wy - (float)(band1 * BANDROWS - 1);   // [0, 1)
                unsigned int qy = (unsigned int)fmaf(wyrel, 2048.0f, 0.5f);
                int lb = tr * BANDS + band1;
                hiB[e][tr] = qy | ((unsigned int)lb << 16);
                rkB[e][tr] = atomicAdd(&lcnt[lb], 1);
            }
        }
    }
    __syncthreads();

    // All-wave redundant scan: lane l holds bin l's 4-rounded count; 6-step
    // shfl_up inclusive scan. Per-item offsets come from variable-lane shfl
    // (no LDS, no barrier). Wave 0 additionally does gcount atomics, pads,
    // and stashes loff/stotal for the flush (visible after next barrier).
    int lane = tid & 63;
    int cl  = lcnt[lane];
    int cel = (cl + 3) & ~3;                 // 4-rounded allocation
    int xg = cel;
    #pragma unroll
    for (int o = 1; o < 64; o <<= 1) {       // full 64-lane inclusive scan
        int yv = __shfl_up(xg, o, 64);
        if (lane >= o) xg += yv;
    }
    int loffv = xg - cel;                    // 4-aligned exclusive offset

    if (tid < 64) {
        loff[tid] = loffv;
        if (tid == 63) stotal = xg;
        int gbin = ((tid >> 5) * BATCH + b) * BANDS + (tid & 31);
        gbase[tid] = cel > 0 ? (int)atomicAdd(&gcount[gbin * GSTRIDE],
                                              (unsigned int)cel) : 0;
        // inert pad items: pk=0, qy rowq=15 -> accum_item touches no rows
        unsigned int hi = (15u << 11) | ((unsigned int)tid << 16);
        for (int j = cl; j < cel; ++j)
            sval[loffv + j] = ((unsigned long long)hi << 32);
    }

    // Stage phase (no barrier needed: offsets are register-resident)
    #pragma unroll
    for (int e = 0; e < EVPT; ++e) {
        #pragma unroll
        for (int tr = 0; tr < 2; ++tr) {
            if (rkA[e][tr] >= 0) {
                int lb = (hiA[e][tr] >> 16) & 63;
                int lo = __shfl(loffv, lb, 64);
                sval[lo + rkA[e][tr]] =
                    (unsigned long long)pkv[e][tr] |
                    ((unsigned long long)hiA[e][tr] << 32);
            }
            if (rkB[e][tr] >= 0) {
                int lb = (hiB[e][tr] >> 16) & 63;
                int lo = __shfl(loffv, lb, 64);
                sval[lo + rkB[e][tr]] =
                    (unsigned long long)pkv[e][tr] |
                    ((unsigned long long)hiB[e][tr] << 32);
            }
        }
    }
    __syncthreads();

    // Flush: runs 4-aligned -> (i..i+3) always same-bin; total multiple of 4.
    int total = stotal;
    for (int i = tid * 4; i < total; i += 4 * BE_THREADS) {
        uint4 q0 = *(const uint4*)&sval[i];       // items i, i+1
        uint4 q1 = *(const uint4*)&sval[i + 2];   // items i+2, i+3
        int lb0 = (q0.y >> 16) & 63;
        int gs0 = gbase[lb0] + (i - loff[lb0]);   // 4-aligned
        int gbin0 = ((lb0 >> 5) * BATCH + b) * BANDS + (lb0 & 31);
        if (gs0 + 3 < CAP) {
            size_t s = (size_t)gbin0 * CAP + gs0;
            *(uint4*)(pk_arr + s) = make_uint4(q0.x, q0.z, q1.x, q1.z);
            *(uint2*)(qy_arr + s) = make_uint2(
                (q0.y & 0xffffu) | ((q0.w & 0xffffu) << 16),
                (q1.y & 0xffffu) | ((q1.w & 0xffffu) << 16));
        }
    }
}

__device__ __forceinline__ unsigned int pack_w(float w, float tg) {
    unsigned int lo16 = (unsigned int)fmaf(w, 1024.0f, 0.5f);
    unsigned int hi16 = (unsigned int)fmaf(w * tg, 1024.0f, 0.5f);
    return lo16 | (hi16 << 16);
}

// Accumulate one item into its 8-row band tile. Integer bilinear decode
// (bit-exact vs floorf path). Dual staggered tiles: even-lx pairs -> ONE
// u64 atomic into A; odd-lx pairs -> ONE u64 atomic into B (B shifted 1 px).
// Zero-valued atomics skipped. No carry crosses 16-bit field boundaries.
__device__ __forceinline__ void accum_item(unsigned int* __restrict__ sA,
                                           unsigned int* __restrict__ sB,
                                           unsigned int pk, unsigned int qy) {
    unsigned int qx = pk >> 12;
    float tg = (float)((pk >> 1) & 2047u) * (1.0f / 2047.0f);
    int p = pk & 1u;

    int lx = (int)(qx >> 11) - 1;              // exact floor
    float fxx = (float)(qx & 2047u) * (1.0f / 2048.0f);

    int rowq = qy >> 11;                       // 0..9 (15 for pad items)
    float fy = (float)(qy & 2047u) * (1.0f / 2048.0f);
    int row_top = rowq - 1;                    // -1..8 (band-local)

    unsigned int* A  = sA + p * HTILE;
    unsigned int* Bb = sB + p * HTILE;

    #pragma unroll
    for (int a = 0; a < 2; ++a) {
        int ry = row_top + a;
        if ((unsigned)ry >= (unsigned)BANDROWS) continue;   // dup covers rest
        float wrow = a ? fy : (1.0f - fy);
        int rb = ry * WW;
        if (lx >= 0 && lx + 1 < WW) {
            unsigned int pl = pack_w(wrow * (1.0f - fxx), tg);
            unsigned int pr = pack_w(wrow * fxx, tg);
            unsigned long long v =
                (unsigned long long)pl | ((unsigned long long)pr << 32);
            if (v == 0ull) continue;           // zero-skip
            if ((lx & 1) == 0) {
                atomicAdd((unsigned long long*)(A + rb + lx), v);
            } else {
                atomicAdd((unsigned long long*)(Bb + rb + lx - 1), v);
            }
        } else if (lx == -1) {
            unsigned int pw = pack_w(wrow * fxx, tg);
            if (pw) atomicAdd(&A[rb], pw);
        } else if (lx == WW - 1) {
            unsigned int pw = pack_w(wrow * (1.0f - fxx), tg);
            if (pw) atomicAdd(&A[rb + lx], pw);
        }
    }
}

// Pass 2: one block per 8-row bin, 1024 threads, 43 KB LDS -> 2 blocks/CU,
// 512 blocks = one full GPU wave. 8 items/iter, software-pipelined.
// Charbonnier smoothness slice between item phase and barrier (early
// threads overlap stragglers' LDS atomics). Fused ratio^2 loss; last block
// (ticket) writes the final scalar.
__global__ __launch_bounds__(1024)
void bin_accum(const unsigned int* __restrict__ gcount,
               const unsigned int* __restrict__ pk_arr,
               const unsigned short* __restrict__ qy_arr,
               const float* __restrict__ flow,
               float* __restrict__ loss_acc,
               unsigned int* __restrict__ done_count,
               float* __restrict__ out) {
    __shared__ __align__(16) unsigned int sA[2 * HTILE];   // 21.5 KB
    __shared__ __align__(16) unsigned int sB[2 * HTILE];   // 21.5 KB
    __shared__ float red[16];
    __shared__ int lastflag;

    int band = blockIdx.x;          // 0..31
    int tr   = blockIdx.y;
    int b    = blockIdx.z;
    int tid  = threadIdx.x;
    int lblk = band + 32 * (tr + 2 * b);   // 0..511 linear block id

    for (int i = tid; i < 2 * HTILE; i += 1024) { sA[i] = 0u; sB[i] = 0u; }
    __syncthreads();

    int gbin = (tr * BATCH + b) * BANDS + band;
    int cnt = min((int)gcount[gbin * GSTRIDE], CAP);
    const unsigned int* pkp = pk_arr + (size_t)gbin * CAP;
    const unsigned short* qyp = qy_arr + (size_t)gbin * CAP;
    const uint4* pk4 = (const uint4*)pkp;    // 4 items per uint4
    const uint4* qy8 = (const uint4*)qyp;    // 8 items per uint4

    int noct = cnt >> 3;
    if (tid < noct) {
        uint4 p0 = pk4[2 * tid], p1 = pk4[2 * tid + 1];
        uint4 q0 = qy8[tid];
        for (int n = tid + 1024; n < noct; n += 1024) {
            uint4 np0 = pk4[2 * n], np1 = pk4[2 * n + 1];   // prefetch
            uint4 nq0 = qy8[n];
            accum_item(sA, sB, p0.x, q0.x & 0xffffu);
            accum_item(sA, sB, p0.y, q0.x >> 16);
            accum_item(sA, sB, p0.z, q0.y & 0xffffu);
            accum_item(sA, sB, p0.w, q0.y >> 16);
            accum_item(sA, sB, p1.x, q0.z & 0xffffu);
            accum_item(sA, sB, p1.y, q0.z >> 16);
            accum_item(sA, sB, p1.z, q0.w & 0xffffu);
            accum_item(sA, sB, p1.w, q0.w >> 16);
            p0 = np0; p1 = np1; q0 = nq0;
        }
        accum_item(sA, sB, p0.x, q0.x & 0xffffu);
        accum_item(sA, sB, p0.y, q0.x >> 16);
        accum_item(sA, sB, p0.z, q0.y & 0xffffu);
        accum_item(sA, sB, p0.w, q0.y >> 16);
        accum_item(sA, sB, p1.x, q0.z & 0xffffu);
        accum_item(sA, sB, p1.y, q0.z >> 16);
        accum_item(sA, sB, p1.z, q0.w & 0xffffu);
        accum_item(sA, sB, p1.w, q0.w >> 16);
    }
    int done = noct << 3;
    int rem = cnt - done;                  // 0 or 4 (counts multiple of 4)
    if (tid < rem) {
        accum_item(sA, sB, pkp[done + tid], (unsigned int)qyp[done + tid]);
    }

    // Charbonnier smoothness slice: pure VALU + regular loads, overlaps the
    // item-phase stragglers before the barrier. 512x1024 threads, one pass.
    float sm = 0.0f;
    {
        const int N4 = BATCH * HWPIX / 4;
        const int H4 = HWPIX / 4;
        const int W4 = WW / 4;
        for (int i = lblk * 1024 + tid; i < N4; i += NBLK_ACC * 1024) {
            int bb = i / H4, u = i - bb * H4;
            int row = u / W4, c4 = u - row * W4;
            const float4* ch0 = (const float4*)(flow + (size_t)bb * 2 * HWPIX);
            const float4* ch1 = ch0 + H4;
            float4 a0 = ch0[u];
            float4 a1 = ch1[u];
            if (row < HH - 1) {
                float4 d0 = ch0[u + W4];
                float4 d1 = ch1[u + W4];
                sm += charb(a0.x - d0.x) + charb(a0.y - d0.y) +
                      charb(a0.z - d0.z) + charb(a0.w - d0.w) +
                      charb(a1.x - d1.x) + charb(a1.y - d1.y) +
                      charb(a1.z - d1.z) + charb(a1.w - d1.w);
            }
            sm += charb(a0.x - a0.y) + charb(a0.y - a0.z) + charb(a0.z - a0.w) +
                  charb(a1.x - a1.y) + charb(a1.y - a1.z) + charb(a1.z - a1.w);
            if (c4 < W4 - 1) {
                float r0 = ((const float*)ch0)[4 * u + 4];
                float r1 = ((const float*)ch1)[4 * u + 4];
                sm += charb(a0.w - r0) + charb(a1.w - r1);
            }
        }
    }
    __syncthreads();

    // Fused ratio^2 loss. pixel p total = A[p] + B[p-1] (B shifted 1 px).
    float v = 0.0f;
    for (int i = tid; i < 2 * HTILE; i += 1024) {
        int px = i - (i / WW) * WW;
        unsigned int u = sA[i] + (px ? sB[i - 1] : 0u);
        float iwe = (float)(u & 0xffffu);
        float its = (float)(u >> 16);
        float r = its / (iwe + 1.024e-6f);
        v += r * r;
    }
    v = fmaf(sm, REG_WEIGHT, v);           // fold smoothness into block sum
    v = wave_reduce_sum(v);
    if ((tid & 63) == 0) red[tid >> 6] = v;
    __syncthreads();
    if (tid == 0) {
        float r = 0.0f;
        #pragma unroll
        for (int k = 0; k < 16; ++k) r += red[k];
        atomicAdd(loss_acc, r);
        __threadfence();
        unsigned int t = atomicAdd(done_count, 1u);
        lastflag = (t == (unsigned)(NBLK_ACC - 1));
    }
    __syncthreads();

    if (lastflag && tid == 0) {
        *out = atomicAdd(loss_acc, 0.0f);  // coherent read of final sum
    }
}

extern "C" void kernel_launch(void* const* d_in, const int* in_sizes, int n_in,
                              void* d_out, int out_size, void* d_ws, size_t ws_size,
                              hipStream_t stream) {
    const float*  flow  = (const float*)d_in[0];
    const float4* ev    = (const float4*)d_in[1];
    float* out = (float*)d_out;

    unsigned int*   gcount     = (unsigned int*)d_ws;
    float*          loss_acc   = (float*)((char*)d_ws + GCOUNT_BYTES);
    unsigned int*   done_count = (unsigned int*)((char*)d_ws + GCOUNT_BYTES + 4);
    unsigned int*   pk_arr     = (unsigned int*)((char*)d_ws + GCOUNT_BYTES + 4096);
    unsigned short* qy_arr     = (unsigned short*)((char*)d_ws + GCOUNT_BYTES + 4096 + PK_BYTES);
    float2*         flowi      = (float2*)((char*)d_ws + GCOUNT_BYTES + 4096 + PK_BYTES + QY_BYTES);

    flow_prep<<<512, 256, 0, stream>>>(flow, flowi, gcount, loss_acc,
                                       done_count);

    int total_ev = BATCH * NEV;
    bin_events<<<total_ev / EV_PER_BLOCK, BE_THREADS, 0, stream>>>(
        flowi, ev, gcount, pk_arr, qy_arr);

    dim3 g2(BANDS, 2, BATCH);
    bin_accum<<<g2, 1024, 0, stream>>>(gcount, pk_arr, qy_arr, flow,
                                       loss_acc, done_count, out);
}

// Round 13
// 133.123 us; speedup vs baseline: 1.0262x; 1.0262x over previous
//
#include <hip/hip_runtime.h>

// Problem constants (from reference)
#define HH 256
#define WW 336
#define HWPIX (HH * WW)          // 86016
#define BATCH 8
#define NEV 262144               // 2^18
#define NEV_SHIFT 18
#define FLOW_SCALING 336.0f
#define REG_WEIGHT 0.001f

// 8-row bands: items binned directly at accum granularity.
#define BANDS 32
#define BANDSHIFT 3
#define BANDROWS 8
#define NBINS (2 * BATCH * BANDS)  // 512 bins: ((tr*8+b)*32+band)
#define CAP 14336                  // slots/bin; mean ~9.2K (multiple of 4)
#define GSTRIDE 16                 // u32 stride/bin: 64B line per counter

// bin_events geometry: 1024 threads x 2 events/thread = 2048 events/block.
// sval worst case = 2048 ev * 2 tref * 2 bands = 8192, + <=192 pad items
// (4-alignment) -> 8384 (65.5 KB LDS); 2 blocks/CU, 32 waves/CU.
// NOTE (round 12 post-mortem): do NOT replace the wave-0 LDS scan with a
// replicated register scan + divergent __shfl for offsets — ds_bpermute
// reads from inactive lanes are undefined under divergent exec (caused a
// silent absmax=8192 corruption) and the redundant scan was slower anyway.
#define BE_THREADS 1024
#define EVPT 2
#define EV_PER_BLOCK (BE_THREADS * EVPT)
#define MAXITEMS 8384

// bin_accum geometry: one block per bin, full 8-row tile in LDS
#define HTILE (BANDROWS * WW)      // 2688 u32 per pol
#define NBLK_ACC NBINS             // 512 accum blocks = 2/CU, no tail

// Workspace layout (split 6-byte items: pk u32 + qy u16):
//   [0]       uint   gcount[NBINS*GSTRIDE]   (32 KB, one bin per 64B line)
//   [32768]   float  loss_acc                (4 B)
//   [32772]   uint   done_count              (4 B)
//   [36864]   uint   pk[NBINS*CAP]           (29.4 MB)
//   [after]   u16    qy[NBINS*CAP]           (14.7 MB)
//   [after]   float2 flowi[BATCH * HWPIX]    (5.5 MB) interleaved (fx, fy)
#define GCOUNT_BYTES (NBINS * GSTRIDE * 4)
#define PK_BYTES ((size_t)NBINS * CAP * 4)
#define QY_BYTES ((size_t)NBINS * CAP * 2)

__device__ __forceinline__ float wave_reduce_sum(float v) {
    #pragma unroll
    for (int o = 32; o > 0; o >>= 1) v += __shfl_down(v, o, 64);
    return v;
}

__device__ __forceinline__ float charb(float d) { return sqrtf(d * d + 1e-6f); }

// Pre-pass: pure flow interleave into float2 (single-gather for bin_events)
// + zero gcount/loss_acc/done_count. Smoothness lives in bin_accum where it
// overlaps LDS-atomic straggler latency.
__global__ __launch_bounds__(256)
void flow_prep(const float* __restrict__ flow, float2* __restrict__ flowi,
               unsigned int* __restrict__ gcount, float* __restrict__ loss_acc,
               unsigned int* __restrict__ done_count) {
    int tid = threadIdx.x;
    if (blockIdx.x == 0) {
        for (int i = tid; i < NBINS * GSTRIDE; i += 256) gcount[i] = 0u;
        if (tid == 0) { *loss_acc = 0.0f; *done_count = 0u; }
    }

    const int N4 = BATCH * HWPIX / 4;
    const int H4 = HWPIX / 4;
    for (int i = blockIdx.x * 256 + tid; i < N4; i += gridDim.x * 256) {
        int b = i / H4, u = i - b * H4;
        const float4* ch0 = (const float4*)(flow + (size_t)b * 2 * HWPIX);
        const float4* ch1 = ch0 + H4;
        float4 a0 = ch0[u];    // x-flow (ch 0)
        float4 a1 = ch1[u];    // y-flow (ch 1)

        float4* fo = (float4*)(flowi + (size_t)b * HWPIX);
        fo[2 * u]     = make_float4(a0.x, a1.x, a0.y, a1.y);
        fo[2 * u + 1] = make_float4(a0.z, a1.z, a0.w, a1.w);
    }
}

// Pass 1: warp events, bin by (tr, b, 8-row band); straddling items get one
// copy per band. Per-bin allocations rounded up to x4 (inert pad items:
// pk=0, rowq=15 -> decode touches no rows), so every flush quad (i..i+3) is
// SAME-BIN and 4-aligned: one uint4 pk-store + one uint2 qy-store per 4
// items (24 B in 2 stores).
__global__ __launch_bounds__(BE_THREADS)
void bin_events(const float2* __restrict__ flowi,
                const float4* __restrict__ ev,
                unsigned int* __restrict__ gcount,
                unsigned int* __restrict__ pk_arr,
                unsigned short* __restrict__ qy_arr) {
    __shared__ int lcnt[64];
    __shared__ int loff[64];
    __shared__ int gbase[64];
    __shared__ int stotal;
    __shared__ __align__(16) unsigned long long sval[MAXITEMS];   // 65.5 KB

    int tid = threadIdx.x;
    if (tid < 64) lcnt[tid] = 0;
    __syncthreads();

    int base = blockIdx.x * EV_PER_BLOCK;
    int b = base >> NEV_SHIFT;       // uniform across block (2048 | NEV)
    const float2* fB = flowi + (size_t)b * HWPIX;

    unsigned int pkv[EVPT][2];
    unsigned int hiA[EVPT][2], hiB[EVPT][2];   // qy16 | lb<<16
    int rkA[EVPT][2], rkB[EVPT][2];            // rank or -1

    #pragma unroll
    for (int e = 0; e < EVPT; ++e) {
        int bn = base + e * BE_THREADS + tid;
        float4 ee = ev[bn];          // t, y, x, pol(+/-1)
        float t = ee.x, y = ee.y, x = ee.z;
        unsigned int p = (ee.w > 0.0f) ? 0u : 1u;

        int iy = (int)y, ix = (int)x;
        float2 f = fB[iy * WW + ix];
        float fx = f.x, fy = f.y;

        #pragma unroll
        for (int tr = 0; tr < 2; ++tr) {
            rkA[e][tr] = -1; rkB[e][tr] = -1;
            float tref  = tr ? 0.0f : 1.0f;
            float tg    = tr ? (1.0f - t) : t;
            float dtS = (tref - t) * FLOW_SCALING;
            float wy = fmaf(dtS, fy, y);
            float wx = fmaf(dtS, fx, x);
            if (!(wx > -1.0f && wx < (float)WW)) continue;
            if (!(wy > -1.0f && wy < (float)HH)) continue;

            int ty = (int)floorf(wy);
            int band0 = -1, band1 = -1;
            if (ty >= 0 && ty < HH) band0 = ty >> BANDSHIFT;
            int r1 = ty + 1;
            if (r1 >= 0 && r1 < HH) {
                int bb = r1 >> BANDSHIFT;
                if (bb != band0) band1 = bb;
            }

            unsigned int qx = (unsigned int)(fmaf(wx, 2048.0f, 2048.5f));
            unsigned int qt = (unsigned int)(tg * 2047.0f + 0.5f);
            pkv[e][tr] = (qx << 12) | (qt << 1) | p;

            if (band0 >= 0) {
                float wyrel = wy - (float)(band0 * BANDROWS - 1);   // [1, 9)
                unsigned int qy = (unsigned int)fmaf(wyrel, 2048.0f, 0.5f);
                int lb = tr * BANDS + band0;
                hiA[e][tr] = qy | ((unsigned int)lb << 16);
                rkA[e][tr] = atomicAdd(&lcnt[lb], 1);
            }
            if (band1 >= 0) {
                float wyrel = wy - (float)(band1 * BANDROWS - 1);   // [0, 1)
                unsigned int qy = (unsigned int)fmaf(wyrel, 2048.0f, 0.5f);
                int lb = tr * BANDS + band1;
                hiB[e][tr] = qy | ((unsigned int)lb << 16);
                rkB[e][tr] = atomicAdd(&lcnt[lb], 1);
            }
        }
    }
    __syncthreads();

    if (tid < 64) {
        int c  = lcnt[tid];
        int ce = (c + 3) & ~3;               // 4-rounded allocation
        int xg = ce;
        #pragma unroll
        for (int o = 1; o < 64; o <<= 1) {   // full 64-lane inclusive scan
            int yv = __shfl_up(xg, o, 64);
            if (tid >= o) xg += yv;
        }
        int lo = xg - ce;                    // 4-aligned (sum of x4s)
        loff[tid] = lo;
        if (tid == 63) stotal = xg;
        int gbin = ((tid >> 5) * BATCH + b) * BANDS + (tid & 31);
        gbase[tid] = ce > 0 ? (int)atomicAdd(&gcount[gbin * GSTRIDE],
                                             (unsigned int)ce) : 0;
        // inert pad items: pk=0, qy rowq=15 -> accum_item touches no rows
        unsigned int hi = (15u << 11) | ((unsigned int)tid << 16);
        for (int j = c; j < ce; ++j)
            sval[lo + j] = ((unsigned long long)hi << 32);
    }
    __syncthreads();

    #pragma unroll
    for (int e = 0; e < EVPT; ++e) {
        #pragma unroll
        for (int tr = 0; tr < 2; ++tr) {
            if (rkA[e][tr] >= 0) {
                int lb = (hiA[e][tr] >> 16) & 63;
                sval[loff[lb] + rkA[e][tr]] =
                    (unsigned long long)pkv[e][tr] |
                    ((unsigned long long)hiA[e][tr] << 32);
            }
            if (rkB[e][tr] >= 0) {
                int lb = (hiB[e][tr] >> 16) & 63;
                sval[loff[lb] + rkB[e][tr]] =
                    (unsigned long long)pkv[e][tr] |
                    ((unsigned long long)hiB[e][tr] << 32);
            }
        }
    }
    __syncthreads();

    // Flush: runs 4-aligned -> (i..i+3) always same-bin; total multiple of 4.
    int total = stotal;
    for (int i = tid * 4; i < total; i += 4 * BE_THREADS) {
        uint4 q0 = *(const uint4*)&sval[i];       // items i, i+1
        uint4 q1 = *(const uint4*)&sval[i + 2];   // items i+2, i+3
        int lb0 = (q0.y >> 16) & 63;
        int gs0 = gbase[lb0] + (i - loff[lb0]);   // 4-aligned
        int gbin0 = ((lb0 >> 5) * BATCH + b) * BANDS + (lb0 & 31);
        if (gs0 + 3 < CAP) {
            size_t s = (size_t)gbin0 * CAP + gs0;
            *(uint4*)(pk_arr + s) = make_uint4(q0.x, q0.z, q1.x, q1.z);
            *(uint2*)(qy_arr + s) = make_uint2(
                (q0.y & 0xffffu) | ((q0.w & 0xffffu) << 16),
                (q1.y & 0xffffu) | ((q1.w & 0xffffu) << 16));
        }
    }
}

__device__ __forceinline__ unsigned int pack_w(float w, float tg) {
    unsigned int lo16 = (unsigned int)fmaf(w, 1024.0f, 0.5f);
    unsigned int hi16 = (unsigned int)fmaf(w * tg, 1024.0f, 0.5f);
    return lo16 | (hi16 << 16);
}

// Accumulate one item into its 8-row band tile. Integer bilinear decode
// (bit-exact vs floorf path). Dual staggered tiles: even-lx pairs -> ONE
// u64 atomic into A; odd-lx pairs -> ONE u64 atomic into B (B shifted 1 px).
// Zero-valued atomics skipped. No carry crosses 16-bit field boundaries.
__device__ __forceinline__ void accum_item(unsigned int* __restrict__ sA,
                                           unsigned int* __restrict__ sB,
                                           unsigned int pk, unsigned int qy) {
    unsigned int qx = pk >> 12;
    float tg = (float)((pk >> 1) & 2047u) * (1.0f / 2047.0f);
    int p = pk & 1u;

    int lx = (int)(qx >> 11) - 1;              // exact floor
    float fxx = (float)(qx & 2047u) * (1.0f / 2048.0f);

    int rowq = qy >> 11;                       // 0..9 (15 for pad items)
    float fy = (float)(qy & 2047u) * (1.0f / 2048.0f);
    int row_top = rowq - 1;                    // -1..8 (band-local)

    unsigned int* A  = sA + p * HTILE;
    unsigned int* Bb = sB + p * HTILE;

    #pragma unroll
    for (int a = 0; a < 2; ++a) {
        int ry = row_top + a;
        if ((unsigned)ry >= (unsigned)BANDROWS) continue;   // dup covers rest
        float wrow = a ? fy : (1.0f - fy);
        int rb = ry * WW;
        if (lx >= 0 && lx + 1 < WW) {
            unsigned int pl = pack_w(wrow * (1.0f - fxx), tg);
            unsigned int pr = pack_w(wrow * fxx, tg);
            unsigned long long v =
                (unsigned long long)pl | ((unsigned long long)pr << 32);
            if (v == 0ull) continue;           // zero-skip
            if ((lx & 1) == 0) {
                atomicAdd((unsigned long long*)(A + rb + lx), v);
            } else {
                atomicAdd((unsigned long long*)(Bb + rb + lx - 1), v);
            }
        } else if (lx == -1) {
            unsigned int pw = pack_w(wrow * fxx, tg);
            if (pw) atomicAdd(&A[rb], pw);
        } else if (lx == WW - 1) {
            unsigned int pw = pack_w(wrow * (1.0f - fxx), tg);
            if (pw) atomicAdd(&A[rb + lx], pw);
        }
    }
}

// Pass 2: one block per 8-row bin, 1024 threads, 43 KB LDS -> 2 blocks/CU,
// 512 blocks = one full GPU wave. 8 items/iter, software-pipelined.
// Charbonnier smoothness slice between item phase and barrier (early
// threads overlap stragglers' LDS atomics). Fused ratio^2 loss; last block
// (ticket) writes the final scalar.
__global__ __launch_bounds__(1024)
void bin_accum(const unsigned int* __restrict__ gcount,
               const unsigned int* __restrict__ pk_arr,
               const unsigned short* __restrict__ qy_arr,
               const float* __restrict__ flow,
               float* __restrict__ loss_acc,
               unsigned int* __restrict__ done_count,
               float* __restrict__ out) {
    __shared__ __align__(16) unsigned int sA[2 * HTILE];   // 21.5 KB
    __shared__ __align__(16) unsigned int sB[2 * HTILE];   // 21.5 KB
    __shared__ float red[16];
    __shared__ int lastflag;

    int band = blockIdx.x;          // 0..31
    int tr   = blockIdx.y;
    int b    = blockIdx.z;
    int tid  = threadIdx.x;
    int lblk = band + 32 * (tr + 2 * b);   // 0..511 linear block id

    for (int i = tid; i < 2 * HTILE; i += 1024) { sA[i] = 0u; sB[i] = 0u; }
    __syncthreads();

    int gbin = (tr * BATCH + b) * BANDS + band;
    int cnt = min((int)gcount[gbin * GSTRIDE], CAP);
    const unsigned int* pkp = pk_arr + (size_t)gbin * CAP;
    const unsigned short* qyp = qy_arr + (size_t)gbin * CAP;
    const uint4* pk4 = (const uint4*)pkp;    // 4 items per uint4
    const uint4* qy8 = (const uint4*)qyp;    // 8 items per uint4

    int noct = cnt >> 3;
    if (tid < noct) {
        uint4 p0 = pk4[2 * tid], p1 = pk4[2 * tid + 1];
        uint4 q0 = qy8[tid];
        for (int n = tid + 1024; n < noct; n += 1024) {
            uint4 np0 = pk4[2 * n], np1 = pk4[2 * n + 1];   // prefetch
            uint4 nq0 = qy8[n];
            accum_item(sA, sB, p0.x, q0.x & 0xffffu);
            accum_item(sA, sB, p0.y, q0.x >> 16);
            accum_item(sA, sB, p0.z, q0.y & 0xffffu);
            accum_item(sA, sB, p0.w, q0.y >> 16);
            accum_item(sA, sB, p1.x, q0.z & 0xffffu);
            accum_item(sA, sB, p1.y, q0.z >> 16);
            accum_item(sA, sB, p1.z, q0.w & 0xffffu);
            accum_item(sA, sB, p1.w, q0.w >> 16);
            p0 = np0; p1 = np1; q0 = nq0;
        }
        accum_item(sA, sB, p0.x, q0.x & 0xffffu);
        accum_item(sA, sB, p0.y, q0.x >> 16);
        accum_item(sA, sB, p0.z, q0.y & 0xffffu);
        accum_item(sA, sB, p0.w, q0.y >> 16);
        accum_item(sA, sB, p1.x, q0.z & 0xffffu);
        accum_item(sA, sB, p1.y, q0.z >> 16);
        accum_item(sA, sB, p1.z, q0.w & 0xffffu);
        accum_item(sA, sB, p1.w, q0.w >> 16);
    }
    int done = noct << 3;
    int rem = cnt - done;                  // 0 or 4 (counts multiple of 4)
    if (tid < rem) {
        accum_item(sA, sB, pkp[done + tid], (unsigned int)qyp[done + tid]);
    }

    // Charbonnier smoothness slice: pure VALU + regular loads, overlaps the
    // item-phase stragglers before the barrier. 512x1024 threads, one pass.
    float sm = 0.0f;
    {
        const int N4 = BATCH * HWPIX / 4;
        const int H4 = HWPIX / 4;
        const int W4 = WW / 4;
        for (int i = lblk * 1024 + tid; i < N4; i += NBLK_ACC * 1024) {
            int bb = i / H4, u = i - bb * H4;
            int row = u / W4, c4 = u - row * W4;
            const float4* ch0 = (const float4*)(flow + (size_t)bb * 2 * HWPIX);
            const float4* ch1 = ch0 + H4;
            float4 a0 = ch0[u];
            float4 a1 = ch1[u];
            if (row < HH - 1) {
                float4 d0 = ch0[u + W4];
                float4 d1 = ch1[u + W4];
                sm += charb(a0.x - d0.x) + charb(a0.y - d0.y) +
                      charb(a0.z - d0.z) + charb(a0.w - d0.w) +
                      charb(a1.x - d1.x) + charb(a1.y - d1.y) +
                      charb(a1.z - d1.z) + charb(a1.w - d1.w);
            }
            sm += charb(a0.x - a0.y) + charb(a0.y - a0.z) + charb(a0.z - a0.w) +
                  charb(a1.x - a1.y) + charb(a1.y - a1.z) + charb(a1.z - a1.w);
            if (c4 < W4 - 1) {
                float r0 = ((const float*)ch0)[4 * u + 4];
                float r1 = ((const float*)ch1)[4 * u + 4];
                sm += charb(a0.w - r0) + charb(a1.w - r1);
            }
        }
    }
    __syncthreads();

    // Fused ratio^2 loss. pixel p total = A[p] + B[p-1] (B shifted 1 px).
    float v = 0.0f;
    for (int i = tid; i < 2 * HTILE; i += 1024) {
        int px = i - (i / WW) * WW;
        unsigned int u = sA[i] + (px ? sB[i - 1] : 0u);
        float iwe = (float)(u & 0xffffu);
        float its = (float)(u >> 16);
        float r = its / (iwe + 1.024e-6f);
        v += r * r;
    }
    v = fmaf(sm, REG_WEIGHT, v);           // fold smoothness into block sum
    v = wave_reduce_sum(v);
    if ((tid & 63) == 0) red[tid >> 6] = v;
    __syncthreads();
    if (tid == 0) {
        float r = 0.0f;
        #pragma unroll
        for (int k = 0; k < 16; ++k) r += red[k];
        atomicAdd(loss_acc, r);
        __threadfence();
        unsigned int t = atomicAdd(done_count, 1u);
        lastflag = (t == (unsigned)(NBLK_ACC - 1));
    }
    __syncthreads();

    if (lastflag && tid == 0) {
        *out = atomicAdd(loss_acc, 0.0f);  // coherent read of final sum
    }
}

extern "C" void kernel_launch(void* const* d_in, const int* in_sizes, int n_in,
                              void* d_out, int out_size, void* d_ws, size_t ws_size,
                              hipStream_t stream) {
    const float*  flow  = (const float*)d_in[0];
    const float4* ev    = (const float4*)d_in[1];
    float* out = (float*)d_out;

    unsigned int*   gcount     = (unsigned int*)d_ws;
    float*          loss_acc   = (float*)((char*)d_ws + GCOUNT_BYTES);
    unsigned int*   done_count = (unsigned int*)((char*)d_ws + GCOUNT_BYTES + 4);
    unsigned int*   pk_arr     = (unsigned int*)((char*)d_ws + GCOUNT_BYTES + 4096);
    unsigned short* qy_arr     = (unsigned short*)((char*)d_ws + GCOUNT_BYTES + 4096 + PK_BYTES);
    float2*         flowi      = (float2*)((char*)d_ws + GCOUNT_BYTES + 4096 + PK_BYTES + QY_BYTES);

    flow_prep<<<512, 256, 0, stream>>>(flow, flowi, gcount, loss_acc,
                                       done_count);

    int total_ev = BATCH * NEV;
    bin_events<<<total_ev / EV_PER_BLOCK, BE_THREADS, 0, stream>>>(
        flowi, ev, gcount, pk_arr, qy_arr);

    dim3 g2(BANDS, 2, BATCH);
    bin_accum<<<g2, 1024, 0, stream>>>(gcount, pk_arr, qy_arr, flow,
                                       loss_acc, done_count, out);
}

// Round 14
// 128.631 us; speedup vs baseline: 1.0620x; 1.0349x over previous
//
#include <hip/hip_runtime.h>

// Problem constants (from reference)
#define HH 256
#define WW 336
#define HWPIX (HH * WW)          // 86016
#define BATCH 8
#define NEV 262144               // 2^18
#define NEV_SHIFT 18
#define FLOW_SCALING 336.0f
#define REG_WEIGHT 0.001f

// 8-row bands: items binned directly at accum granularity.
#define BANDS 32
#define BANDSHIFT 3
#define BANDROWS 8
#define NBINS (2 * BATCH * BANDS)  // 512 bins: ((tr*8+b)*32+band)

// Fixed per-(block,bin) item regions: block blkin (128 blocks/batch) owns
// slots [blkin*MPB, blkin*MPB+MPB) of each of its 64 (tr,band) bins.
// Per-block-per-bin count: mean ~68, sigma ~8 -> MPB=160 = mean+11sigma.
// cnt[gbin*128+blkin] is ALWAYS written (even 0) -> no zeroing pass needed.
#define BPB 128                    // blocks per batch = NEV / EV_PER_BLOCK
#define MPB 160                    // slots per (block,bin), multiple of 4

// bin_events geometry: 1024 threads x 2 events/thread = 2048 events/block.
// sval worst case = 2048 ev * 2 tref * 2 bands = 8192, + <=192 pad items
// (4-alignment) -> 8384 (65.5 KB LDS); 2 blocks/CU, 32 waves/CU.
// NOTE (round 12 post-mortem): do NOT replace the wave-0 LDS scan with a
// replicated register scan + divergent __shfl for offsets - ds_bpermute
// reads from inactive lanes are undefined under divergent exec.
#define BE_THREADS 1024
#define EVPT 2
#define EV_PER_BLOCK (BE_THREADS * EVPT)
#define MAXITEMS 8384

// bin_accum geometry: one block per bin, full 8-row tile in LDS
#define HTILE (BANDROWS * WW)      // 2688 u32 per pol
#define NBLK_ACC NBINS             // 512 accum blocks = 2/CU, no tail

// Workspace layout (split 6-byte items: pk u32 + qy u16; NOTHING zeroed):
//   [0]       uint   pk[NBINS*BPB*MPB]   (41.9 MB)
//   [after]   u16    qy[NBINS*BPB*MPB]   (21.0 MB)
//   [after]   uint   cnt[NBINS*BPB]      (256 KB)
#define SLOTS_PER_BIN ((size_t)BPB * MPB)
#define PK_BYTES ((size_t)NBINS * SLOTS_PER_BIN * 4)
#define QY_BYTES ((size_t)NBINS * SLOTS_PER_BIN * 2)

__device__ __forceinline__ float wave_reduce_sum(float v) {
    #pragma unroll
    for (int o = 32; o > 0; o >>= 1) v += __shfl_down(v, o, 64);
    return v;
}

__device__ __forceinline__ float charb(float d) { return sqrtf(d * d + 1e-6f); }

// Pass 1: warp events, bin by (tr, b, 8-row band); straddling items get one
// copy per band. Flow gathered directly from the two planes (L2-resident;
// round-6-verified). Per-bin allocations rounded up to x4 (inert pad items:
// pk=0, rowq=15), so every flush quad (i..i+3) is SAME-BIN and 4-aligned.
// Items land in the block's FIXED region of each bin (no global atomics).
__global__ __launch_bounds__(BE_THREADS)
void bin_events(const float* __restrict__ flow,
                const float4* __restrict__ ev,
                unsigned int* __restrict__ pk_arr,
                unsigned short* __restrict__ qy_arr,
                unsigned int* __restrict__ cnt_arr) {
    __shared__ int lcnt[64];
    __shared__ int loff[64];
    __shared__ int stotal;
    __shared__ __align__(16) unsigned long long sval[MAXITEMS];   // 65.5 KB

    int tid = threadIdx.x;
    if (tid < 64) lcnt[tid] = 0;
    __syncthreads();

    int base = blockIdx.x * EV_PER_BLOCK;
    int b    = base >> NEV_SHIFT;          // batch (uniform across block)
    int blkin = blockIdx.x & (BPB - 1);    // block index within batch
    const float* fxp = flow + (size_t)b * 2 * HWPIX;   // x-flow plane (ch 0)
    const float* fyp = fxp + HWPIX;                    // y-flow plane (ch 1)

    unsigned int pkv[EVPT][2];
    unsigned int hiA[EVPT][2], hiB[EVPT][2];   // qy16 | lb<<16
    int rkA[EVPT][2], rkB[EVPT][2];            // rank or -1

    #pragma unroll
    for (int e = 0; e < EVPT; ++e) {
        int bn = base + e * BE_THREADS + tid;
        float4 ee = ev[bn];          // t, y, x, pol(+/-1)
        float t = ee.x, y = ee.y, x = ee.z;
        unsigned int p = (ee.w > 0.0f) ? 0u : 1u;

        int iy = (int)y, ix = (int)x;
        int off = iy * WW + ix;
        float fx = fxp[off];
        float fy = fyp[off];

        #pragma unroll
        for (int tr = 0; tr < 2; ++tr) {
            rkA[e][tr] = -1; rkB[e][tr] = -1;
            float tref  = tr ? 0.0f : 1.0f;
            float tg    = tr ? (1.0f - t) : t;
            float dtS = (tref - t) * FLOW_SCALING;
            float wy = fmaf(dtS, fy, y);
            float wx = fmaf(dtS, fx, x);
            if (!(wx > -1.0f && wx < (float)WW)) continue;
            if (!(wy > -1.0f && wy < (float)HH)) continue;

            int ty = (int)floorf(wy);
            int band0 = -1, band1 = -1;
            if (ty >= 0 && ty < HH) band0 = ty >> BANDSHIFT;
            int r1 = ty + 1;
            if (r1 >= 0 && r1 < HH) {
                int bb = r1 >> BANDSHIFT;
                if (bb != band0) band1 = bb;
            }

            unsigned int qx = (unsigned int)(fmaf(wx, 2048.0f, 2048.5f));
            unsigned int qt = (unsigned int)(tg * 2047.0f + 0.5f);
            pkv[e][tr] = (qx << 12) | (qt << 1) | p;

            if (band0 >= 0) {
                float wyrel = wy - (float)(band0 * BANDROWS - 1);   // [1, 9)
                unsigned int qy = (unsigned int)fmaf(wyrel, 2048.0f, 0.5f);
                int lb = tr * BANDS + band0;
                hiA[e][tr] = qy | ((unsigned int)lb << 16);
                rkA[e][tr] = atomicAdd(&lcnt[lb], 1);
            }
            if (band1 >= 0) {
                float wyrel = wy - (float)(band1 * BANDROWS - 1);   // [0, 1)
                unsigned int qy = (unsigned int)fmaf(wyrel, 2048.0f, 0.5f);
                int lb = tr * BANDS + band1;
                hiB[e][tr] = qy | ((unsigned int)lb << 16);
                rkB[e][tr] = atomicAdd(&lcnt[lb], 1);
            }
        }
    }
    __syncthreads();

    if (tid < 64) {
        int c  = lcnt[tid];
        int ce = (c + 3) & ~3;               // 4-rounded allocation
        int xg = ce;
        #pragma unroll
        for (int o = 1; o < 64; o <<= 1) {   // full 64-lane inclusive scan
            int yv = __shfl_up(xg, o, 64);
            if (tid >= o) xg += yv;
        }
        int lo = xg - ce;                    // 4-aligned (sum of x4s)
        loff[tid] = lo;
        if (tid == 63) stotal = xg;
        int gbin = ((tid >> 5) * BATCH + b) * BANDS + (tid & 31);
        cnt_arr[gbin * BPB + blkin] = (unsigned int)min(ce, MPB);
        // inert pad items: pk=0, qy rowq=15 -> accum_item touches no rows
        unsigned int hi = (15u << 11) | ((unsigned int)tid << 16);
        for (int j = c; j < ce; ++j)
            sval[lo + j] = ((unsigned long long)hi << 32);
    }
    __syncthreads();

    #pragma unroll
    for (int e = 0; e < EVPT; ++e) {
        #pragma unroll
        for (int tr = 0; tr < 2; ++tr) {
            if (rkA[e][tr] >= 0) {
                int lb = (hiA[e][tr] >> 16) & 63;
                sval[loff[lb] + rkA[e][tr]] =
                    (unsigned long long)pkv[e][tr] |
                    ((unsigned long long)hiA[e][tr] << 32);
            }
            if (rkB[e][tr] >= 0) {
                int lb = (hiB[e][tr] >> 16) & 63;
                sval[loff[lb] + rkB[e][tr]] =
                    (unsigned long long)pkv[e][tr] |
                    ((unsigned long long)hiB[e][tr] << 32);
            }
        }
    }
    __syncthreads();

    // Flush: runs 4-aligned -> (i..i+3) always same-bin; total multiple of 4.
    // Slot = bin region + blkin*MPB + rank (fixed; ranks >= MPB dropped).
    int total = stotal;
    for (int i = tid * 4; i < total; i += 4 * BE_THREADS) {
        uint4 q0 = *(const uint4*)&sval[i];       // items i, i+1
        uint4 q1 = *(const uint4*)&sval[i + 2];   // items i+2, i+3
        int lb0 = (q0.y >> 16) & 63;
        int rank0 = i - loff[lb0];                // 4-aligned
        if (rank0 + 3 < MPB) {
            int gbin0 = ((lb0 >> 5) * BATCH + b) * BANDS + (lb0 & 31);
            size_t s = ((size_t)gbin0 * BPB + blkin) * MPB + rank0;
            *(uint4*)(pk_arr + s) = make_uint4(q0.x, q0.z, q1.x, q1.z);
            *(uint2*)(qy_arr + s) = make_uint2(
                (q0.y & 0xffffu) | ((q0.w & 0xffffu) << 16),
                (q1.y & 0xffffu) | ((q1.w & 0xffffu) << 16));
        }
    }
}

__device__ __forceinline__ unsigned int pack_w(float w, float tg) {
    unsigned int lo16 = (unsigned int)fmaf(w, 1024.0f, 0.5f);
    unsigned int hi16 = (unsigned int)fmaf(w * tg, 1024.0f, 0.5f);
    return lo16 | (hi16 << 16);
}

// Accumulate one item into its 8-row band tile. Integer bilinear decode
// (bit-exact vs floorf path). Dual staggered tiles: even-lx pairs -> ONE
// u64 atomic into A; odd-lx pairs -> ONE u64 atomic into B (B shifted 1 px).
// Zero-valued atomics skipped. No carry crosses 16-bit field boundaries.
__device__ __forceinline__ void accum_item(unsigned int* __restrict__ sA,
                                           unsigned int* __restrict__ sB,
                                           unsigned int pk, unsigned int qy) {
    unsigned int qx = pk >> 12;
    float tg = (float)((pk >> 1) & 2047u) * (1.0f / 2047.0f);
    int p = pk & 1u;

    int lx = (int)(qx >> 11) - 1;              // exact floor
    float fxx = (float)(qx & 2047u) * (1.0f / 2048.0f);

    int rowq = qy >> 11;                       // 0..9 (15 for pad items)
    float fy = (float)(qy & 2047u) * (1.0f / 2048.0f);
    int row_top = rowq - 1;                    // -1..8 (band-local)

    unsigned int* A  = sA + p * HTILE;
    unsigned int* Bb = sB + p * HTILE;

    #pragma unroll
    for (int a = 0; a < 2; ++a) {
        int ry = row_top + a;
        if ((unsigned)ry >= (unsigned)BANDROWS) continue;   // dup covers rest
        float wrow = a ? fy : (1.0f - fy);
        int rb = ry * WW;
        if (lx >= 0 && lx + 1 < WW) {
            unsigned int pl = pack_w(wrow * (1.0f - fxx), tg);
            unsigned int pr = pack_w(wrow * fxx, tg);
            unsigned long long v =
                (unsigned long long)pl | ((unsigned long long)pr << 32);
            if (v == 0ull) continue;           // zero-skip
            if ((lx & 1) == 0) {
                atomicAdd((unsigned long long*)(A + rb + lx), v);
            } else {
                atomicAdd((unsigned long long*)(Bb + rb + lx - 1), v);
            }
        } else if (lx == -1) {
            unsigned int pw = pack_w(wrow * fxx, tg);
            if (pw) atomicAdd(&A[rb], pw);
        } else if (lx == WW - 1) {
            unsigned int pw = pack_w(wrow * (1.0f - fxx), tg);
            if (pw) atomicAdd(&A[rb + lx], pw);
        }
    }
}

// Pass 2: one block per 8-row bin, 1024 threads, 43 KB LDS -> 2 blocks/CU,
// 512 blocks = one full GPU wave. 128 count-bounded chunks, 8 threads/chunk,
// 4 items/iter. Charbonnier smoothness slice between item phase and barrier.
// Fused ratio^2 loss; each block atomicAdds its partial straight into out
// (harness memsets out to 0 before launch; no ticket, no scalar workspace).
__global__ __launch_bounds__(1024)
void bin_accum(const unsigned int* __restrict__ pk_arr,
               const unsigned short* __restrict__ qy_arr,
               const unsigned int* __restrict__ cnt_arr,
               const float* __restrict__ flow,
               float* __restrict__ out) {
    __shared__ __align__(16) unsigned int sA[2 * HTILE];   // 21.5 KB
    __shared__ __align__(16) unsigned int sB[2 * HTILE];   // 21.5 KB
    __shared__ int scnt[BPB];
    __shared__ float red[16];

    int band = blockIdx.x;          // 0..31
    int tr   = blockIdx.y;
    int b    = blockIdx.z;
    int tid  = threadIdx.x;
    int lblk = band + 32 * (tr + 2 * b);   // 0..511 linear block id

    int gbin = (tr * BATCH + b) * BANDS + band;

    for (int i = tid; i < 2 * HTILE; i += 1024) { sA[i] = 0u; sB[i] = 0u; }
    if (tid < BPB) scnt[tid] = (int)cnt_arr[gbin * BPB + tid];
    __syncthreads();

    // Item phase: chunk = producer block, 8 threads per chunk.
    {
        int chunk = tid >> 3, sub = tid & 7;
        const unsigned int* pkc =
            pk_arr + ((size_t)gbin * BPB + chunk) * MPB;
        const unsigned short* qyc =
            qy_arr + ((size_t)gbin * BPB + chunk) * MPB;
        int c = scnt[chunk];                 // multiple of 4, <= MPB
        for (int idx = sub * 4; idx < c; idx += 32) {
            uint4 p = *(const uint4*)(pkc + idx);
            uint2 q = *(const uint2*)(qyc + idx);
            accum_item(sA, sB, p.x, q.x & 0xffffu);
            accum_item(sA, sB, p.y, q.x >> 16);
            accum_item(sA, sB, p.z, q.y & 0xffffu);
            accum_item(sA, sB, p.w, q.y >> 16);
        }
    }

    // Charbonnier smoothness slice: pure VALU + regular loads, overlaps the
    // item-phase stragglers before the barrier. 512x1024 threads, one pass.
    float sm = 0.0f;
    {
        const int N4 = BATCH * HWPIX / 4;
        const int H4 = HWPIX / 4;
        const int W4 = WW / 4;
        for (int i = lblk * 1024 + tid; i < N4; i += NBLK_ACC * 1024) {
            int bb = i / H4, u = i - bb * H4;
            int row = u / W4, c4 = u - row * W4;
            const float4* ch0 = (const float4*)(flow + (size_t)bb * 2 * HWPIX);
            const float4* ch1 = ch0 + H4;
            float4 a0 = ch0[u];
            float4 a1 = ch1[u];
            if (row < HH - 1) {
                float4 d0 = ch0[u + W4];
                float4 d1 = ch1[u + W4];
                sm += charb(a0.x - d0.x) + charb(a0.y - d0.y) +
                      charb(a0.z - d0.z) + charb(a0.w - d0.w) +
                      charb(a1.x - d1.x) + charb(a1.y - d1.y) +
                      charb(a1.z - d1.z) + charb(a1.w - d1.w);
            }
            sm += charb(a0.x - a0.y) + charb(a0.y - a0.z) + charb(a0.z - a0.w) +
                  charb(a1.x - a1.y) + charb(a1.y - a1.z) + charb(a1.z - a1.w);
            if (c4 < W4 - 1) {
                float r0 = ((const float*)ch0)[4 * u + 4];
                float r1 = ((const float*)ch1)[4 * u + 4];
                sm += charb(a0.w - r0) + charb(a1.w - r1);
            }
        }
    }
    __syncthreads();

    // Fused ratio^2 loss. pixel p total = A[p] + B[p-1] (B shifted 1 px).
    float v = 0.0f;
    for (int i = tid; i < 2 * HTILE; i += 1024) {
        int px = i - (i / WW) * WW;
        unsigned int u = sA[i] + (px ? sB[i - 1] : 0u);
        float iwe = (float)(u & 0xffffu);
        float its = (float)(u >> 16);
        float r = its / (iwe + 1.024e-6f);
        v += r * r;
    }
    v = fmaf(sm, REG_WEIGHT, v);           // fold smoothness into block sum
    v = wave_reduce_sum(v);
    if ((tid & 63) == 0) red[tid >> 6] = v;
    __syncthreads();
    if (tid == 0) {
        float r = 0.0f;
        #pragma unroll
        for (int k = 0; k < 16; ++k) r += red[k];
        atomicAdd(out, r);                 // device-scope; out pre-zeroed
    }
}

extern "C" void kernel_launch(void* const* d_in, const int* in_sizes, int n_in,
                              void* d_out, int out_size, void* d_ws, size_t ws_size,
                              hipStream_t stream) {
    const float*  flow  = (const float*)d_in[0];
    const float4* ev    = (const float4*)d_in[1];
    float* out = (float*)d_out;

    unsigned int*   pk_arr  = (unsigned int*)d_ws;
    unsigned short* qy_arr  = (unsigned short*)((char*)d_ws + PK_BYTES);
    unsigned int*   cnt_arr = (unsigned int*)((char*)d_ws + PK_BYTES + QY_BYTES);

    int total_ev = BATCH * NEV;
    bin_events<<<total_ev / EV_PER_BLOCK, BE_THREADS, 0, stream>>>(
        flow, ev, pk_arr, qy_arr, cnt_arr);

    dim3 g2(BANDS, 2, BATCH);
    bin_accum<<<g2, 1024, 0, stream>>>(pk_arr, qy_arr, cnt_arr, flow, out);
}